// Round 13
// baseline (67.654 us; speedup 1.0000x reference)
//
#include <hip/hip_runtime.h>
#include <hip/hip_bf16.h>

typedef __attribute__((ext_vector_type(8))) short bf16x8;
typedef __attribute__((ext_vector_type(4))) float f32x4;

#define CDIM 192
#define NTOK 196
#define LTOT 392
#define NBE 64

__device__ __forceinline__ ushort f2bf(float f) {
  uint u = __float_as_uint(f);
  u = (u + 0x7FFFu + ((u >> 16) & 1u)) >> 16;
  return (ushort)u;
}
__device__ __forceinline__ float bf2f(ushort h) {
  return __uint_as_float(((uint)h) << 16);
}
__device__ __forceinline__ uint pk2(float lo, float hi) {
  __hip_bfloat162 t = __float22bfloat162_rn(float2{lo, hi});
  uint r;
  __builtin_memcpy(&r, &t, 4);
  return r;
}
__device__ __forceinline__ float wave_reduce(float a) {
#pragma unroll
  for (int off = 32; off > 0; off >>= 1) a += __shfl_xor(a, off);
  return a;
}

// ---------------- prep: fold BN (bf16 weights), u3/u4/K via wave-reductions ---
__global__ __launch_bounds__(256) void prep_kernel(
    const float* __restrict__ w1, const float* __restrict__ b1, const float* __restrict__ g1,
    const float* __restrict__ be1, const float* __restrict__ m1, const float* __restrict__ v1,
    const float* __restrict__ w2, const float* __restrict__ b2, const float* __restrict__ g2,
    const float* __restrict__ be2, const float* __restrict__ m2, const float* __restrict__ v2,
    const float* __restrict__ w3, const float* __restrict__ b3,
    const float* __restrict__ w4, const float* __restrict__ b4,
    const float* __restrict__ w5, const float* __restrict__ b5,
    ushort* __restrict__ w1b, ushort* __restrict__ w2b,
    float* __restrict__ u3, float* __restrict__ u4, float* __restrict__ cvecs,
    float* __restrict__ Kc) {
  const int bid = blockIdx.x;
  const int wid = threadIdx.x >> 6, lane = threadIdx.x & 63;
  if (bid < NBE) {
    for (int i = bid * 256 + threadIdx.x; i < 74112; i += NBE * 256) {
      if (i < 36864) {
        int o = i / CDIM;
        float inv = g1[o] * rsqrtf(v1[o] + 1e-5f);
        w1b[i] = f2bf(w1[i] * inv);
      } else if (i < 73728) {
        int j = i - 36864; int o = j / CDIM;
        float inv = g2[o] * rsqrtf(v2[o] + 1e-5f);
        w2b[j] = f2bf(w2[j] * inv);
      } else {
        int k = i - 73728; int h = k / CDIM, o = k % CDIM;
        const float* bb = h ? b2 : b1; const float* gg = h ? g2 : g1;
        const float* bee = h ? be2 : be1;
        const float* mm = h ? m2 : m1; const float* vv = h ? v2 : v1;
        float inv = gg[o] * rsqrtf(vv[o] + 1e-5f);
        cvecs[k] = (bb[o] - mm[o]) * inv + bee[o];
      }
    }
  } else if (bid < NBE + 48) {            // u3: wave per output j
    int j = (bid - NBE) * 4 + wid;
    float a = 0.f;
    for (int c = lane; c < CDIM; c += 64) a += w5[c] * w3[c * CDIM + j];
    a = wave_reduce(a);
    if (lane == 0) u3[j] = a;
  } else if (bid < NBE + 48 + 98) {       // u4: wave per output j
    int j = (bid - NBE - 48) * 4 + wid;
    float a = 0.f;
    for (int o = lane; o < 784; o += 64)
      a += w5[CDIM + o] * (w4[o * 784 + j] + w4[o * 784 + j + LTOT]);
    a = wave_reduce(a);
    if (lane == 0) u4[j] = a;
  } else {                                // Kc: single wave
    if (wid == 0) {
      float a = 0.f;
      for (int i = lane; i < CDIM + 784; i += 64)
        a += (i < CDIM) ? w5[i] * b3[i] : w5[i] * b4[i - CDIM];
      a = wave_reduce(a);
      if (lane == 0) Kc[0] = a + b5[0];
    }
  }
}

// ---- fused: phi (in LDS, never global) + s + W.  1 block per b, 12 waves. ----
// LDS: phiL[404*192] bf16 (swz ^(l&7)<<4) | u4s[400] | csL[384] | sArr[192]
#define PHIL_BYTES (404 * 384)
#define OFF_U4S PHIL_BYTES
#define OFF_CSL (OFF_U4S + 1600)
#define OFF_SARR (OFF_CSL + 1536)
#define SMEM_BYTES (OFF_SARR + 768)

extern __shared__ char smem[];

__global__ __launch_bounds__(768, 1) void fused_kernel(
    const float* __restrict__ x, const float* __restrict__ y,
    const ushort* __restrict__ w1b, const ushort* __restrict__ w2b,
    const float* __restrict__ cvecs, const float* __restrict__ u4,
    const float* __restrict__ u3, const float* __restrict__ Kc,
    float* __restrict__ Wg) {
  const int b = blockIdx.x;
  ushort* phiL = (ushort*)smem;
  float* u4s = (float*)(smem + OFF_U4S);
  float* csL = (float*)(smem + OFF_CSL);
  float* sArr = (float*)(smem + OFF_SARR);
  const int tid = threadIdx.x;
  for (int i = tid; i < 400; i += 768) u4s[i] = (i < LTOT) ? u4[i] : 0.f;
  for (int i = tid; i < 384; i += 768) csL[i] = cvecs[i];

  const int w = tid >> 6, lane = tid & 63;
  const int lrow = lane & 15, kgrp = lane >> 4;
  const int c = w * 16 + lrow;            // wave w owns c-tile w (12 waves = 12 tiles)

  bf16x8 bfr0[6], bfr1[6];                // B-frags for both halves
#pragma unroll
  for (int kk = 0; kk < 6; kk++) {
    bfr0[kk] = *(const bf16x8*)(w1b + (size_t)c * CDIM + kk * 32 + kgrp * 8);
    bfr1[kk] = *(const bf16x8*)(w2b + (size_t)c * CDIM + kk * 32 + kgrp * 8);
  }
  __syncthreads();
  const float csr0 = csL[c], csr1 = csL[CDIM + c];

  const float4* xb4 = (const float4*)(x + (size_t)b * NTOK * CDIM);
  const float4* yb4 = (const float4*)(y + (size_t)b * NTOK * CDIM);
  float sp = 0.f;

  auto loadpf = [&](int R, float4* pf) {
    if (R < 14) {
      const float4* s4 = (R < 7) ? xb4 : yb4;
      const int base = (R % 7) * 1536;
#pragma unroll
      for (int p = 0; p < 2; p++) {
        const int fi = base + p * 768 + tid;
        pf[p] = (fi < 9408) ? s4[fi] : float4{0.f, 0.f, 0.f, 0.f};
      }
    }
  };
  float4 pfA[2], pfB[2];
  loadpf(0, pfA);
  loadpf(1, pfB);

  for (int R = 0; R < 14; R++) {
    const int h = R / 7, r = R % 7;
    // stage pfA -> phiL rows (bf16 A-tile, in-place with future phi rows)
#pragma unroll
    for (int p = 0; p < 2; p++) {
      const int fi = r * 1536 + p * 768 + tid;
      if (fi < 9408) {
        const int row = fi / 48, c4 = fi - row * 48;
        const int l = h * NTOK + row;
        uint2 wv;
        wv.x = pk2(pfA[p].x, pfA[p].y);
        wv.y = pk2(pfA[p].z, pfA[p].w);
        uint addr = (uint)(l * 384 + c4 * 8) ^ (uint)((l & 7) << 4);
        *(uint2*)((char*)phiL + addr) = wv;
      }
    }
    pfA[0] = pfB[0]; pfA[1] = pfB[1];
    loadpf(R + 2, pfB);                   // 2-deep prefetch
    __syncthreads();                      // A(R) staged

    // MFMA: 2 row-tiles of 16 (tail round: only tile 0 partially valid)
    const bool t1ok = (r * 32 + 16) < NTOK;
    f32x4 acc0 = {0.f, 0.f, 0.f, 0.f}, acc1 = {0.f, 0.f, 0.f, 0.f};
    {
      bf16x8 a0[6], a1[6];
      const int l0 = h * NTOK + r * 32 + lrow;
#pragma unroll
      for (int kk = 0; kk < 6; kk++) {
        uint ad0 = (uint)(l0 * 384 + (kk * 32 + kgrp * 8) * 2) ^ (uint)((l0 & 7) << 4);
        a0[kk] = *(const bf16x8*)((const char*)phiL + ad0);
        const int l1 = l0 + 16;
        uint ad1 = (uint)(l1 * 384 + (kk * 32 + kgrp * 8) * 2) ^ (uint)((l1 & 7) << 4);
        a1[kk] = *(const bf16x8*)((const char*)phiL + ad1);
      }
      if (h == 0) {
#pragma unroll
        for (int kk = 0; kk < 6; kk++) {
          acc0 = __builtin_amdgcn_mfma_f32_16x16x32_bf16(a0[kk], bfr0[kk], acc0, 0, 0, 0);
          if (t1ok) acc1 = __builtin_amdgcn_mfma_f32_16x16x32_bf16(a1[kk], bfr0[kk], acc1, 0, 0, 0);
        }
      } else {
#pragma unroll
        for (int kk = 0; kk < 6; kk++) {
          acc0 = __builtin_amdgcn_mfma_f32_16x16x32_bf16(a0[kk], bfr1[kk], acc0, 0, 0, 0);
          if (t1ok) acc1 = __builtin_amdgcn_mfma_f32_16x16x32_bf16(a1[kk], bfr1[kk], acc1, 0, 0, 0);
        }
      }
    }
    __syncthreads();                      // A(R) fully consumed

    // epilogue: phi values overwrite the A rows in LDS; s partials
    {
      const float csr = h ? csr1 : csr0;
#pragma unroll
      for (int tt = 0; tt < 2; tt++) {
        const int rb = r * 32 + tt * 16;
        if (rb < NTOK) {
          const f32x4 ac = tt ? acc1 : acc0;
          const float v0 = fmaxf(ac[0] + csr, 0.f);
          const float v1 = fmaxf(ac[1] + csr, 0.f);
          const float v2 = fmaxf(ac[2] + csr, 0.f);
          const float v3 = fmaxf(ac[3] + csr, 0.f);
          const uint p01 = pk2(v0, v1), p23 = pk2(v2, v3);
          const int row0 = rb + 4 * kgrp;
#pragma unroll
          for (int j = 0; j < 4; j++) {
            const int row = row0 + j;
            if (row < NTOK) {
              const int l = h * NTOK + row;
              uint addr = (uint)(l * 384 + c * 2) ^ (uint)((l & 7) << 4);
              const uint piece = (j == 0) ? (p01 & 0xFFFFu) : (j == 1) ? (p01 >> 16)
                               : (j == 2) ? (p23 & 0xFFFFu) : (p23 >> 16);
              *(ushort*)((char*)phiL + addr) = (ushort)piece;
              const float vj = (j == 0) ? v0 : (j == 1) ? v1 : (j == 2) ? v2 : v3;
              sp += u4s[l] * vj;
            }
          }
        }
      }
    }
  }

  // s reduction (c fixed per lane) -> sArr, then coeff in place
  sp += __shfl_xor(sp, 16);
  sp += __shfl_xor(sp, 32);
  if (kgrp == 0) sArr[c] = sp;
  __syncthreads();
  for (int i = tid; i < CDIM; i += 768) sArr[i] = u3[i] + sArr[i];
  __syncthreads();

  // W phase: 4-lane group per row, read phi from LDS, write W to global
  const float Kv = Kc[0];
  const int grp = tid >> 2, g4 = tid & 3;
  for (int l = grp; l < LTOT; l += 192) {
    float acc = 0.f;
#pragma unroll
    for (int q = 0; q < 12; q++) {
      const int cc = g4 * 48 + q * 4;
      uint addr = (uint)(l * 384 + cc * 2) ^ (uint)((l & 7) << 4);
      ushort4 v = *(const ushort4*)((const char*)phiL + addr);
      acc += sArr[cc] * bf2f(v.x) + sArr[cc + 1] * bf2f(v.y) +
             sArr[cc + 2] * bf2f(v.z) + sArr[cc + 3] * bf2f(v.w);
    }
    acc += __shfl_xor(acc, 1);
    acc += __shfl_xor(acc, 2);
    if (g4 == 0) Wg[b * LTOT + l] = acc + Kv;
  }
}

// ------- out: block = (b, n-tile of 28). out = x*Wx + y*Wy, transposed. ------
__global__ __launch_bounds__(256) void out_kernel(
    const float* __restrict__ x, const float* __restrict__ y,
    const float* __restrict__ Wg, float* __restrict__ out) {
  const int bid = blockIdx.x;
  const int b = bid / 7, nt = bid % 7;
  const int n0 = nt * 28;
  __shared__ float Wl[56];
  __shared__ float tile[28][193];
  const int tid = threadIdx.x;
  if (tid < 56) {
    const int lg = (tid < 28) ? (n0 + tid) : (NTOK + n0 + tid - 28);
    Wl[tid] = Wg[b * LTOT + lg];
  }
  __syncthreads();
  for (int i = tid; i < 28 * 48; i += 256) {
    const int nl = i / 48, c4 = (i % 48) * 4;
    const size_t xi = ((size_t)b * NTOK + n0 + nl) * CDIM + c4;
    const float4 xv = *(const float4*)&x[xi];
    const float4 yv = *(const float4*)&y[xi];
    const float wx = Wl[nl], wy = Wl[28 + nl];
    tile[nl][c4 + 0] = xv.x * wx + yv.x * wy;
    tile[nl][c4 + 1] = xv.y * wx + yv.y * wy;
    tile[nl][c4 + 2] = xv.z * wx + yv.z * wy;
    tile[nl][c4 + 3] = xv.w * wx + yv.w * wy;
  }
  __syncthreads();
  for (int i = tid; i < CDIM * 7; i += 256) {
    const int c = i / 7, nq = i % 7;
    float4 o;
    o.x = tile[nq * 4 + 0][c]; o.y = tile[nq * 4 + 1][c];
    o.z = tile[nq * 4 + 2][c]; o.w = tile[nq * 4 + 3][c];
    *(float4*)&out[((size_t)b * CDIM + c) * NTOK + n0 + nq * 4] = o;
  }
}

extern "C" void kernel_launch(void* const* d_in, const int* in_sizes, int n_in,
                              void* d_out, int out_size, void* d_ws, size_t ws_size,
                              hipStream_t stream) {
  const float* x   = (const float*)d_in[0];
  const float* y   = (const float*)d_in[1];
  const float* w1  = (const float*)d_in[2];
  const float* b1  = (const float*)d_in[3];
  const float* g1  = (const float*)d_in[4];
  const float* be1 = (const float*)d_in[5];
  const float* m1  = (const float*)d_in[6];
  const float* v1  = (const float*)d_in[7];
  const float* w2  = (const float*)d_in[8];
  const float* b2  = (const float*)d_in[9];
  const float* g2  = (const float*)d_in[10];
  const float* be2 = (const float*)d_in[11];
  const float* m2  = (const float*)d_in[12];
  const float* v2  = (const float*)d_in[13];
  const float* w3  = (const float*)d_in[14];
  const float* b3  = (const float*)d_in[15];
  const float* w4  = (const float*)d_in[16];
  const float* b4  = (const float*)d_in[17];
  const float* w5  = (const float*)d_in[18];
  const float* b5  = (const float*)d_in[19];
  float* out = (float*)d_out;

  char* ws = (char*)d_ws;
  ushort* w1b  = (ushort*)ws;             // 73728 B
  ushort* w2b  = (ushort*)(ws + 73728);   // 73728 B
  float* fbase = (float*)(ws + 147456);
  float* u3    = fbase;                   // 192
  float* u4    = fbase + 192;             // 392
  float* cvecs = fbase + 584;             // 384 (c1|c2)
  float* Kc    = fbase + 968;             // 1
  float* Wg    = fbase + 976;             // 256*392 = 100352

  prep_kernel<<<211, 256, 0, stream>>>(w1, b1, g1, be1, m1, v1,
                                       w2, b2, g2, be2, m2, v2,
                                       w3, b3, w4, b4, w5, b5,
                                       w1b, w2b, u3, u4, cvecs, Kc);
  fused_kernel<<<256, 768, SMEM_BYTES, stream>>>(x, y, w1b, w2b, cvecs, u4,
                                                 u3, Kc, Wg);
  out_kernel<<<256 * 7, 256, 0, stream>>>(x, y, Wg, out);
}

// Round 14
// 63.415 us; speedup vs baseline: 1.0668x; 1.0668x over previous
//
#include <hip/hip_runtime.h>
#include <hip/hip_bf16.h>

typedef __attribute__((ext_vector_type(8))) short bf16x8;
typedef __attribute__((ext_vector_type(4))) float f32x4;

#define CDIM 192
#define NTOK 196
#define LTOT 392
#define NBE 64

__device__ __forceinline__ ushort f2bf(float f) {
  uint u = __float_as_uint(f);
  u = (u + 0x7FFFu + ((u >> 16) & 1u)) >> 16;
  return (ushort)u;
}
__device__ __forceinline__ float bf2f(ushort h) {
  return __uint_as_float(((uint)h) << 16);
}
__device__ __forceinline__ uint pk2(float lo, float hi) {
  __hip_bfloat162 t = __float22bfloat162_rn(float2{lo, hi});
  uint r;
  __builtin_memcpy(&r, &t, 4);
  return r;
}
__device__ __forceinline__ float wave_reduce(float a) {
#pragma unroll
  for (int off = 32; off > 0; off >>= 1) a += __shfl_xor(a, off);
  return a;
}
// Raw barrier: LDS-visibility only (lgkmcnt), does NOT drain in-flight global
// loads (unlike __syncthreads' vmcnt(0) drain) — keeps prefetches pipelined.
__device__ __forceinline__ void barL() {
  asm volatile("s_waitcnt lgkmcnt(0)" ::: "memory");
  __builtin_amdgcn_s_barrier();
  __builtin_amdgcn_sched_barrier(0);
}

// ---------------- prep: fold BN (bf16 weights), u3/u4/K via wave-reductions ---
__global__ __launch_bounds__(256) void prep_kernel(
    const float* __restrict__ w1, const float* __restrict__ b1, const float* __restrict__ g1,
    const float* __restrict__ be1, const float* __restrict__ m1, const float* __restrict__ v1,
    const float* __restrict__ w2, const float* __restrict__ b2, const float* __restrict__ g2,
    const float* __restrict__ be2, const float* __restrict__ m2, const float* __restrict__ v2,
    const float* __restrict__ w3, const float* __restrict__ b3,
    const float* __restrict__ w4, const float* __restrict__ b4,
    const float* __restrict__ w5, const float* __restrict__ b5,
    ushort* __restrict__ w1b, ushort* __restrict__ w2b,
    float* __restrict__ u3, float* __restrict__ u4, float* __restrict__ cvecs,
    float* __restrict__ Kc) {
  const int bid = blockIdx.x;
  const int wid = threadIdx.x >> 6, lane = threadIdx.x & 63;
  if (bid < NBE) {
    for (int i = bid * 256 + threadIdx.x; i < 74112; i += NBE * 256) {
      if (i < 36864) {
        int o = i / CDIM;
        float inv = g1[o] * rsqrtf(v1[o] + 1e-5f);
        w1b[i] = f2bf(w1[i] * inv);
      } else if (i < 73728) {
        int j = i - 36864; int o = j / CDIM;
        float inv = g2[o] * rsqrtf(v2[o] + 1e-5f);
        w2b[j] = f2bf(w2[j] * inv);
      } else {
        int k = i - 73728; int h = k / CDIM, o = k % CDIM;
        const float* bb = h ? b2 : b1; const float* gg = h ? g2 : g1;
        const float* bee = h ? be2 : be1;
        const float* mm = h ? m2 : m1; const float* vv = h ? v2 : v1;
        float inv = gg[o] * rsqrtf(vv[o] + 1e-5f);
        cvecs[k] = (bb[o] - mm[o]) * inv + bee[o];
      }
    }
  } else if (bid < NBE + 48) {            // u3: wave per output j
    int j = (bid - NBE) * 4 + wid;
    float a = 0.f;
    for (int c = lane; c < CDIM; c += 64) a += w5[c] * w3[c * CDIM + j];
    a = wave_reduce(a);
    if (lane == 0) u3[j] = a;
  } else if (bid < NBE + 48 + 98) {       // u4: wave per output j
    int j = (bid - NBE - 48) * 4 + wid;
    float a = 0.f;
    for (int o = lane; o < 784; o += 64)
      a += w5[CDIM + o] * (w4[o * 784 + j] + w4[o * 784 + j + LTOT]);
    a = wave_reduce(a);
    if (lane == 0) u4[j] = a;
  } else {                                // Kc: single wave
    if (wid == 0) {
      float a = 0.f;
      for (int i = lane; i < CDIM + 784; i += 64)
        a += (i < CDIM) ? w5[i] * b3[i] : w5[i] * b4[i - CDIM];
      a = wave_reduce(a);
      if (lane == 0) Kc[0] = a + b5[0];
    }
  }
}

// ---- fused: phi (in LDS, never global) + s + W.  1 block per b, 12 waves. ----
// LDS: phiL[404*192] bf16 (swz ^(l&7)<<4) | u4s[400] | csL[384] | sArr[192]
#define PHIL_BYTES (404 * 384)
#define OFF_U4S PHIL_BYTES
#define OFF_CSL (OFF_U4S + 1600)
#define OFF_SARR (OFF_CSL + 1536)
#define SMEM_BYTES (OFF_SARR + 768)

extern __shared__ char smem[];

__global__ __launch_bounds__(768, 1) void fused_kernel(
    const float* __restrict__ x, const float* __restrict__ y,
    const ushort* __restrict__ w1b, const ushort* __restrict__ w2b,
    const float* __restrict__ cvecs, const float* __restrict__ u4,
    const float* __restrict__ u3, const float* __restrict__ Kc,
    float* __restrict__ Wg) {
  const int b = blockIdx.x;
  ushort* phiL = (ushort*)smem;
  float* u4s = (float*)(smem + OFF_U4S);
  float* csL = (float*)(smem + OFF_CSL);
  float* sArr = (float*)(smem + OFF_SARR);
  const int tid = threadIdx.x;
  for (int i = tid; i < 400; i += 768) u4s[i] = (i < LTOT) ? u4[i] : 0.f;
  for (int i = tid; i < 384; i += 768) csL[i] = cvecs[i];

  const int w = tid >> 6, lane = tid & 63;
  const int lrow = lane & 15, kgrp = lane >> 4;
  const int c = w * 16 + lrow;            // wave w owns c-tile w (12 waves = 12 tiles)

  bf16x8 bfr0[6], bfr1[6];                // B-frags for both halves
#pragma unroll
  for (int kk = 0; kk < 6; kk++) {
    bfr0[kk] = *(const bf16x8*)(w1b + (size_t)c * CDIM + kk * 32 + kgrp * 8);
    bfr1[kk] = *(const bf16x8*)(w2b + (size_t)c * CDIM + kk * 32 + kgrp * 8);
  }
  barL();
  const float csr0 = csL[c], csr1 = csL[CDIM + c];

  const float4* xb4 = (const float4*)(x + (size_t)b * NTOK * CDIM);
  const float4* yb4 = (const float4*)(y + (size_t)b * NTOK * CDIM);
  float sp = 0.f;

  auto loadpf = [&](int R, float4* pf) {
    if (R < 14) {
      const float4* s4 = (R < 7) ? xb4 : yb4;
      const int base = (R % 7) * 1536;
#pragma unroll
      for (int p = 0; p < 2; p++) {
        const int fi = base + p * 768 + tid;
        pf[p] = (fi < 9408) ? s4[fi] : float4{0.f, 0.f, 0.f, 0.f};
      }
    }
  };
  float4 pfA[2], pfB[2];
  loadpf(0, pfA);
  loadpf(1, pfB);

  for (int R = 0; R < 14; R++) {
    const int h = R / 7, r = R % 7;
    // stage pfA -> phiL rows (bf16 A-tile, in-place with future phi rows)
#pragma unroll
    for (int p = 0; p < 2; p++) {
      const int fi = r * 1536 + p * 768 + tid;
      if (fi < 9408) {
        const int row = fi / 48, c4 = fi - row * 48;
        const int l = h * NTOK + row;
        uint2 wv;
        wv.x = pk2(pfA[p].x, pfA[p].y);
        wv.y = pk2(pfA[p].z, pfA[p].w);
        uint addr = (uint)(l * 384 + c4 * 8) ^ (uint)((l & 7) << 4);
        *(uint2*)((char*)phiL + addr) = wv;
      }
    }
    pfA[0] = pfB[0]; pfA[1] = pfB[1];     // vmcnt wait lands here (1 round after issue)
    loadpf(R + 2, pfB);                   // stays in flight across raw barriers
    barL();                               // A(R) staged & visible

    // MFMA: 2 row-tiles of 16 (tail round: only tile 0 partially valid)
    const bool t1ok = (r * 32 + 16) < NTOK;
    f32x4 acc0 = {0.f, 0.f, 0.f, 0.f}, acc1 = {0.f, 0.f, 0.f, 0.f};
    {
      bf16x8 a0[6], a1[6];
      const int l0 = h * NTOK + r * 32 + lrow;
#pragma unroll
      for (int kk = 0; kk < 6; kk++) {
        uint ad0 = (uint)(l0 * 384 + (kk * 32 + kgrp * 8) * 2) ^ (uint)((l0 & 7) << 4);
        a0[kk] = *(const bf16x8*)((const char*)phiL + ad0);
        const int l1 = l0 + 16;
        uint ad1 = (uint)(l1 * 384 + (kk * 32 + kgrp * 8) * 2) ^ (uint)((l1 & 7) << 4);
        a1[kk] = *(const bf16x8*)((const char*)phiL + ad1);
      }
      if (h == 0) {
#pragma unroll
        for (int kk = 0; kk < 6; kk++) {
          acc0 = __builtin_amdgcn_mfma_f32_16x16x32_bf16(a0[kk], bfr0[kk], acc0, 0, 0, 0);
          if (t1ok) acc1 = __builtin_amdgcn_mfma_f32_16x16x32_bf16(a1[kk], bfr0[kk], acc1, 0, 0, 0);
        }
      } else {
#pragma unroll
        for (int kk = 0; kk < 6; kk++) {
          acc0 = __builtin_amdgcn_mfma_f32_16x16x32_bf16(a0[kk], bfr1[kk], acc0, 0, 0, 0);
          if (t1ok) acc1 = __builtin_amdgcn_mfma_f32_16x16x32_bf16(a1[kk], bfr1[kk], acc1, 0, 0, 0);
        }
      }
    }
    barL();                               // A(R) consumed by all waves

    // epilogue: phi values overwrite the A rows in LDS; s partials
    {
      const float csr = h ? csr1 : csr0;
#pragma unroll
      for (int tt = 0; tt < 2; tt++) {
        const int rb = r * 32 + tt * 16;
        if (rb < NTOK) {
          const f32x4 ac = tt ? acc1 : acc0;
          const float v0 = fmaxf(ac[0] + csr, 0.f);
          const float v1 = fmaxf(ac[1] + csr, 0.f);
          const float v2 = fmaxf(ac[2] + csr, 0.f);
          const float v3 = fmaxf(ac[3] + csr, 0.f);
          const uint p01 = pk2(v0, v1), p23 = pk2(v2, v3);
          const int row0 = rb + 4 * kgrp;
#pragma unroll
          for (int j = 0; j < 4; j++) {
            const int row = row0 + j;
            if (row < NTOK) {
              const int l = h * NTOK + row;
              uint addr = (uint)(l * 384 + c * 2) ^ (uint)((l & 7) << 4);
              const uint piece = (j == 0) ? (p01 & 0xFFFFu) : (j == 1) ? (p01 >> 16)
                               : (j == 2) ? (p23 & 0xFFFFu) : (p23 >> 16);
              *(ushort*)((char*)phiL + addr) = (ushort)piece;
              const float vj = (j == 0) ? v0 : (j == 1) ? v1 : (j == 2) ? v2 : v3;
              sp += u4s[l] * vj;
            }
          }
        }
      }
    }
    // epilogue(R) writes rows of round R only; stage(R+1) writes disjoint rows,
    // and the next barL orders epilogue writes before round R+1's ds_reads.
  }

  // s reduction (c fixed per lane) -> sArr, then coeff in place
  sp += __shfl_xor(sp, 16);
  sp += __shfl_xor(sp, 32);
  if (kgrp == 0) sArr[c] = sp;
  barL();
  for (int i = tid; i < CDIM; i += 768) sArr[i] = u3[i] + sArr[i];
  barL();

  // W phase: 4-lane group per row, read phi from LDS, write W to global
  const float Kv = Kc[0];
  const int grp = tid >> 2, g4 = tid & 3;
  for (int l = grp; l < LTOT; l += 192) {
    float acc = 0.f;
#pragma unroll
    for (int q = 0; q < 12; q++) {
      const int cc = g4 * 48 + q * 4;
      uint addr = (uint)(l * 384 + cc * 2) ^ (uint)((l & 7) << 4);
      ushort4 v = *(const ushort4*)((const char*)phiL + addr);
      acc += sArr[cc] * bf2f(v.x) + sArr[cc + 1] * bf2f(v.y) +
             sArr[cc + 2] * bf2f(v.z) + sArr[cc + 3] * bf2f(v.w);
    }
    acc += __shfl_xor(acc, 1);
    acc += __shfl_xor(acc, 2);
    if (g4 == 0) Wg[b * LTOT + l] = acc + Kv;
  }
}

// ------- out: block = (b, n-tile of 28). out = x*Wx + y*Wy, transposed. ------
__global__ __launch_bounds__(256) void out_kernel(
    const float* __restrict__ x, const float* __restrict__ y,
    const float* __restrict__ Wg, float* __restrict__ out) {
  const int bid = blockIdx.x;
  const int b = bid / 7, nt = bid % 7;
  const int n0 = nt * 28;
  __shared__ float Wl[56];
  __shared__ float tile[28][193];
  const int tid = threadIdx.x;
  if (tid < 56) {
    const int lg = (tid < 28) ? (n0 + tid) : (NTOK + n0 + tid - 28);
    Wl[tid] = Wg[b * LTOT + lg];
  }
  __syncthreads();
  for (int i = tid; i < 28 * 48; i += 256) {
    const int nl = i / 48, c4 = (i % 48) * 4;
    const size_t xi = ((size_t)b * NTOK + n0 + nl) * CDIM + c4;
    const float4 xv = *(const float4*)&x[xi];
    const float4 yv = *(const float4*)&y[xi];
    const float wx = Wl[nl], wy = Wl[28 + nl];
    tile[nl][c4 + 0] = xv.x * wx + yv.x * wy;
    tile[nl][c4 + 1] = xv.y * wx + yv.y * wy;
    tile[nl][c4 + 2] = xv.z * wx + yv.z * wy;
    tile[nl][c4 + 3] = xv.w * wx + yv.w * wy;
  }
  __syncthreads();
  for (int i = tid; i < CDIM * 7; i += 256) {
    const int c = i / 7, nq = i % 7;
    float4 o;
    o.x = tile[nq * 4 + 0][c]; o.y = tile[nq * 4 + 1][c];
    o.z = tile[nq * 4 + 2][c]; o.w = tile[nq * 4 + 3][c];
    *(float4*)&out[((size_t)b * CDIM + c) * NTOK + n0 + nq * 4] = o;
  }
}

extern "C" void kernel_launch(void* const* d_in, const int* in_sizes, int n_in,
                              void* d_out, int out_size, void* d_ws, size_t ws_size,
                              hipStream_t stream) {
  const float* x   = (const float*)d_in[0];
  const float* y   = (const float*)d_in[1];
  const float* w1  = (const float*)d_in[2];
  const float* b1  = (const float*)d_in[3];
  const float* g1  = (const float*)d_in[4];
  const float* be1 = (const float*)d_in[5];
  const float* m1  = (const float*)d_in[6];
  const float* v1  = (const float*)d_in[7];
  const float* w2  = (const float*)d_in[8];
  const float* b2  = (const float*)d_in[9];
  const float* g2  = (const float*)d_in[10];
  const float* be2 = (const float*)d_in[11];
  const float* m2  = (const float*)d_in[12];
  const float* v2  = (const float*)d_in[13];
  const float* w3  = (const float*)d_in[14];
  const float* b3  = (const float*)d_in[15];
  const float* w4  = (const float*)d_in[16];
  const float* b4  = (const float*)d_in[17];
  const float* w5  = (const float*)d_in[18];
  const float* b5  = (const float*)d_in[19];
  float* out = (float*)d_out;

  char* ws = (char*)d_ws;
  ushort* w1b  = (ushort*)ws;             // 73728 B
  ushort* w2b  = (ushort*)(ws + 73728);   // 73728 B
  float* fbase = (float*)(ws + 147456);
  float* u3    = fbase;                   // 192
  float* u4    = fbase + 192;             // 392
  float* cvecs = fbase + 584;             // 384 (c1|c2)
  float* Kc    = fbase + 968;             // 1
  float* Wg    = fbase + 976;             // 256*392 = 100352

  prep_kernel<<<211, 256, 0, stream>>>(w1, b1, g1, be1, m1, v1,
                                       w2, b2, g2, be2, m2, v2,
                                       w3, b3, w4, b4, w5, b5,
                                       w1b, w2b, u3, u4, cvecs, Kc);
  fused_kernel<<<256, 768, SMEM_BYTES, stream>>>(x, y, w1b, w2b, cvecs, u4,
                                                 u3, Kc, Wg);
  out_kernel<<<256 * 7, 256, 0, stream>>>(x, y, Wg, out);
}

// Round 15
// 61.373 us; speedup vs baseline: 1.1024x; 1.0333x over previous
//
#include <hip/hip_runtime.h>
#include <hip/hip_bf16.h>

typedef __attribute__((ext_vector_type(8))) short bf16x8;
typedef __attribute__((ext_vector_type(4))) float f32x4;

#define CDIM 192
#define NTOK 196
#define LTOT 392
#define NBE 64

__device__ __forceinline__ ushort f2bf(float f) {
  uint u = __float_as_uint(f);
  u = (u + 0x7FFFu + ((u >> 16) & 1u)) >> 16;
  return (ushort)u;
}
__device__ __forceinline__ float bf2f(ushort h) {
  return __uint_as_float(((uint)h) << 16);
}
__device__ __forceinline__ uint pk2(float lo, float hi) {
  __hip_bfloat162 t = __float22bfloat162_rn(float2{lo, hi});
  uint r;
  __builtin_memcpy(&r, &t, 4);
  return r;
}
__device__ __forceinline__ float wave_reduce(float a) {
#pragma unroll
  for (int off = 32; off > 0; off >>= 1) a += __shfl_xor(a, off);
  return a;
}
// Raw barrier: LDS-visibility only (lgkmcnt); does NOT drain in-flight global
// loads (unlike __syncthreads' vmcnt(0) drain) — keeps prefetches pipelined.
__device__ __forceinline__ void barL() {
  asm volatile("s_waitcnt lgkmcnt(0)" ::: "memory");
  __builtin_amdgcn_s_barrier();
  __builtin_amdgcn_sched_barrier(0);
}

// ---------------- prep: fold BN (bf16 weights), u3/u4/K via wave-reductions ---
__global__ __launch_bounds__(256) void prep_kernel(
    const float* __restrict__ w1, const float* __restrict__ b1, const float* __restrict__ g1,
    const float* __restrict__ be1, const float* __restrict__ m1, const float* __restrict__ v1,
    const float* __restrict__ w2, const float* __restrict__ b2, const float* __restrict__ g2,
    const float* __restrict__ be2, const float* __restrict__ m2, const float* __restrict__ v2,
    const float* __restrict__ w3, const float* __restrict__ b3,
    const float* __restrict__ w4, const float* __restrict__ b4,
    const float* __restrict__ w5, const float* __restrict__ b5,
    ushort* __restrict__ w1b, ushort* __restrict__ w2b,
    float* __restrict__ u3, float* __restrict__ u4, float* __restrict__ cvecs,
    float* __restrict__ Kc) {
  const int bid = blockIdx.x;
  const int wid = threadIdx.x >> 6, lane = threadIdx.x & 63;
  if (bid < NBE) {
    for (int i = bid * 256 + threadIdx.x; i < 74112; i += NBE * 256) {
      if (i < 36864) {
        int o = i / CDIM;
        float inv = g1[o] * rsqrtf(v1[o] + 1e-5f);
        w1b[i] = f2bf(w1[i] * inv);
      } else if (i < 73728) {
        int j = i - 36864; int o = j / CDIM;
        float inv = g2[o] * rsqrtf(v2[o] + 1e-5f);
        w2b[j] = f2bf(w2[j] * inv);
      } else {
        int k = i - 73728; int h = k / CDIM, o = k % CDIM;
        const float* bb = h ? b2 : b1; const float* gg = h ? g2 : g1;
        const float* bee = h ? be2 : be1;
        const float* mm = h ? m2 : m1; const float* vv = h ? v2 : v1;
        float inv = gg[o] * rsqrtf(vv[o] + 1e-5f);
        cvecs[k] = (bb[o] - mm[o]) * inv + bee[o];
      }
    }
  } else if (bid < NBE + 48) {            // u3: wave per output j
    int j = (bid - NBE) * 4 + wid;
    float a = 0.f;
    for (int c = lane; c < CDIM; c += 64) a += w5[c] * w3[c * CDIM + j];
    a = wave_reduce(a);
    if (lane == 0) u3[j] = a;
  } else if (bid < NBE + 48 + 98) {       // u4: wave per output j
    int j = (bid - NBE - 48) * 4 + wid;
    float a = 0.f;
    for (int o = lane; o < 784; o += 64)
      a += w5[CDIM + o] * (w4[o * 784 + j] + w4[o * 784 + j + LTOT]);
    a = wave_reduce(a);
    if (lane == 0) u4[j] = a;
  } else {                                // Kc: single wave
    if (wid == 0) {
      float a = 0.f;
      for (int i = lane; i < CDIM + 784; i += 64)
        a += (i < CDIM) ? w5[i] * b3[i] : w5[i] * b4[i - CDIM];
      a = wave_reduce(a);
      if (lane == 0) Kc[0] = a + b5[0];
    }
  }
}

// --- fully fused: phi (in LDS) + s + W + out.  1 block per b, 12 waves. ------
// LDS: phiL[404*192]bf16 swz | u4s[408] | csL[384] | sArr[192] | Wl[392]
#define PHIL_BYTES (404 * 384)
#define OFF_U4S PHIL_BYTES
#define OFF_CSL (OFF_U4S + 1632)
#define OFF_SARR (OFF_CSL + 1536)
#define OFF_WL (OFF_SARR + 768)
#define SMEM_BYTES (OFF_WL + 1568)

extern __shared__ char smem[];

__global__ __launch_bounds__(768, 1) void fused_kernel(
    const float* __restrict__ x, const float* __restrict__ y,
    const ushort* __restrict__ w1b, const ushort* __restrict__ w2b,
    const float* __restrict__ cvecs, const float* __restrict__ u4,
    const float* __restrict__ u3, const float* __restrict__ Kc,
    float* __restrict__ out) {
  const int b = blockIdx.x;
  ushort* phiL = (ushort*)smem;
  float* u4s = (float*)(smem + OFF_U4S);
  float* csL = (float*)(smem + OFF_CSL);
  float* sArr = (float*)(smem + OFF_SARR);
  float* Wl = (float*)(smem + OFF_WL);
  const int tid = threadIdx.x;
  for (int i = tid; i < 408; i += 768) u4s[i] = (i < LTOT) ? u4[i] : 0.f;
  for (int i = tid; i < 384; i += 768) csL[i] = cvecs[i];

  const int w = tid >> 6, lane = tid & 63;
  const int lrow = lane & 15, kgrp = lane >> 4;
  const int c = w * 16 + lrow;            // wave w owns c-tile w (12 waves)

  bf16x8 bfr0[6], bfr1[6];                // B-frags for both halves
#pragma unroll
  for (int kk = 0; kk < 6; kk++) {
    bfr0[kk] = *(const bf16x8*)(w1b + (size_t)c * CDIM + kk * 32 + kgrp * 8);
    bfr1[kk] = *(const bf16x8*)(w2b + (size_t)c * CDIM + kk * 32 + kgrp * 8);
  }
  barL();
  const float csr0 = csL[c], csr1 = csL[CDIM + c];

  const float4* xb4 = (const float4*)(x + (size_t)b * NTOK * CDIM);
  const float4* yb4 = (const float4*)(y + (size_t)b * NTOK * CDIM);
  float sp = 0.f;

  // 8 rounds of 64 rows (196 = 3*64 + 4 per half)
  auto loadpf = [&](int R, float4* pf) {
    if (R < 8) {
      const float4* s4 = (R < 4) ? xb4 : yb4;
      const int base = (R & 3) * 3072;
#pragma unroll
      for (int p = 0; p < 4; p++) {
        const int fi = base + p * 768 + tid;
        pf[p] = (fi < 9408) ? s4[fi] : float4{0.f, 0.f, 0.f, 0.f};
      }
    }
  };
  float4 pfA[4], pfB[4];
  loadpf(0, pfA);
  loadpf(1, pfB);

  for (int R = 0; R < 8; R++) {
    const int h = R >> 2, r = R & 3;
    // stage pfA -> phiL rows (bf16 A-tile, in-place with future phi rows)
#pragma unroll
    for (int p = 0; p < 4; p++) {
      const int fi = r * 3072 + p * 768 + tid;
      if (fi < 9408) {
        const int row = fi / 48, c4 = fi - row * 48;
        const int l = h * NTOK + row;
        uint2 wv;
        wv.x = pk2(pfA[p].x, pfA[p].y);
        wv.y = pk2(pfA[p].z, pfA[p].w);
        uint addr = (uint)(l * 384 + c4 * 8) ^ (uint)((l & 7) << 4);
        *(uint2*)((char*)phiL + addr) = wv;
      }
    }
#pragma unroll
    for (int p = 0; p < 4; p++) pfA[p] = pfB[p];  // vmcnt wait lands here
    loadpf(R + 2, pfB);                   // stays in flight across raw barriers
    barL();                               // A(R) staged & visible

    // MFMA: 4 row-tiles of 16 (tail round r=3: only tile 0, rows 192..195)
    f32x4 acc[4];
#pragma unroll
    for (int tt = 0; tt < 4; tt++) acc[tt] = f32x4{0.f, 0.f, 0.f, 0.f};
#pragma unroll
    for (int tt = 0; tt < 4; tt++) {
      const int rb = r * 64 + tt * 16;
      if (rb < NTOK) {
        bf16x8 af[6];
        const int l0 = h * NTOK + rb + lrow;
#pragma unroll
        for (int kk = 0; kk < 6; kk++) {
          uint ad = (uint)(l0 * 384 + (kk * 32 + kgrp * 8) * 2) ^ (uint)((l0 & 7) << 4);
          af[kk] = *(const bf16x8*)((const char*)phiL + ad);
        }
        if (h == 0) {
#pragma unroll
          for (int kk = 0; kk < 6; kk++)
            acc[tt] = __builtin_amdgcn_mfma_f32_16x16x32_bf16(af[kk], bfr0[kk], acc[tt], 0, 0, 0);
        } else {
#pragma unroll
          for (int kk = 0; kk < 6; kk++)
            acc[tt] = __builtin_amdgcn_mfma_f32_16x16x32_bf16(af[kk], bfr1[kk], acc[tt], 0, 0, 0);
        }
      }
    }
    barL();                               // A(R) consumed by all waves

    // epilogue: phi overwrites the A rows in LDS; s partials
    const float csr = h ? csr1 : csr0;
#pragma unroll
    for (int tt = 0; tt < 4; tt++) {
      const int rb = r * 64 + tt * 16;
      if (rb < NTOK) {
        const float v0 = fmaxf(acc[tt][0] + csr, 0.f);
        const float v1 = fmaxf(acc[tt][1] + csr, 0.f);
        const float v2 = fmaxf(acc[tt][2] + csr, 0.f);
        const float v3 = fmaxf(acc[tt][3] + csr, 0.f);
        const uint p01 = pk2(v0, v1), p23 = pk2(v2, v3);
        const int row0 = rb + 4 * kgrp;
#pragma unroll
        for (int j = 0; j < 4; j++) {
          const int row = row0 + j;
          if (row < NTOK) {
            const int l = h * NTOK + row;
            uint addr = (uint)(l * 384 + c * 2) ^ (uint)((l & 7) << 4);
            const uint piece = (j == 0) ? (p01 & 0xFFFFu) : (j == 1) ? (p01 >> 16)
                             : (j == 2) ? (p23 & 0xFFFFu) : (p23 >> 16);
            *(ushort*)((char*)phiL + addr) = (ushort)piece;
            const float vj = (j == 0) ? v0 : (j == 1) ? v1 : (j == 2) ? v2 : v3;
            sp += u4s[l] * vj;
          }
        }
      }
    }
    // epilogue(R) rows disjoint from stage(R+1) rows; next barL orders
    // epilogue writes before round R+1's ds_reads.
  }

  // s reduction (c fixed per lane) -> sArr -> coeff
  sp += __shfl_xor(sp, 16);
  sp += __shfl_xor(sp, 32);
  if (kgrp == 0) sArr[c] = sp;
  barL();
  for (int i = tid; i < CDIM; i += 768) sArr[i] = u3[i] + sArr[i];
  barL();

  // W phase: 4-lane group per row, phi from LDS, W -> Wl (LDS)
  const float Kv = Kc[0];
  const int grp = tid >> 2, g4 = tid & 3;
  for (int l = grp; l < LTOT; l += 192) {
    float acc = 0.f;
#pragma unroll
    for (int q = 0; q < 12; q++) {
      const int cc = g4 * 48 + q * 4;
      uint addr = (uint)(l * 384 + cc * 2) ^ (uint)((l & 7) << 4);
      ushort4 v = *(const ushort4*)((const char*)phiL + addr);
      acc += sArr[cc] * bf2f(v.x) + sArr[cc + 1] * bf2f(v.y) +
             sArr[cc + 2] * bf2f(v.z) + sArr[cc + 3] * bf2f(v.w);
    }
    acc += __shfl_xor(acc, 1);
    acc += __shfl_xor(acc, 2);
    if (g4 == 0) Wl[l] = acc + Kv;
  }

  // out phase: 7 n-tiles of 28; phiL region reused as f32 tile buffer.
  float* tileF = (float*)smem;
  const float* xb = x + (size_t)b * NTOK * CDIM;
  const float* yb = y + (size_t)b * NTOK * CDIM;
  float4 px[2], py[2];
  auto loadT = [&](int nt) {
    if (nt < 7) {
#pragma unroll
      for (int p = 0; p < 2; p++) {
        const int i = p * 768 + tid;
        if (i < 1344) {
          const size_t xi = (size_t)(nt * 28 + i / 48) * CDIM + (i % 48) * 4;
          px[p] = *(const float4*)&xb[xi];
          py[p] = *(const float4*)&yb[xi];
        }
      }
    }
  };
  loadT(0);
  for (int nt = 0; nt < 7; nt++) {
    const int n0 = nt * 28;
    barL();  // nt=0: W-phase phiL reads + Wl writes done; else: prev store done
#pragma unroll
    for (int p = 0; p < 2; p++) {
      const int i = p * 768 + tid;
      if (i < 1344) {
        const int nl = i / 48, c4 = (i % 48) * 4;
        const float wx = Wl[n0 + nl], wy = Wl[NTOK + n0 + nl];
        tileF[nl * 193 + c4 + 0] = px[p].x * wx + py[p].x * wy;
        tileF[nl * 193 + c4 + 1] = px[p].y * wx + py[p].y * wy;
        tileF[nl * 193 + c4 + 2] = px[p].z * wx + py[p].z * wy;
        tileF[nl * 193 + c4 + 3] = px[p].w * wx + py[p].w * wy;
      }
    }
    loadT(nt + 1);                        // next tile's loads fly over store
    barL();                               // tile written
#pragma unroll
    for (int p = 0; p < 2; p++) {
      const int i = p * 768 + tid;
      if (i < 1344) {
        const int cc = i / 7, nq = i % 7;
        float4 o;
        o.x = tileF[(nq * 4 + 0) * 193 + cc];
        o.y = tileF[(nq * 4 + 1) * 193 + cc];
        o.z = tileF[(nq * 4 + 2) * 193 + cc];
        o.w = tileF[(nq * 4 + 3) * 193 + cc];
        *(float4*)&out[((size_t)b * CDIM + cc) * NTOK + n0 + nq * 4] = o;
      }
    }
  }
}

extern "C" void kernel_launch(void* const* d_in, const int* in_sizes, int n_in,
                              void* d_out, int out_size, void* d_ws, size_t ws_size,
                              hipStream_t stream) {
  const float* x   = (const float*)d_in[0];
  const float* y   = (const float*)d_in[1];
  const float* w1  = (const float*)d_in[2];
  const float* b1  = (const float*)d_in[3];
  const float* g1  = (const float*)d_in[4];
  const float* be1 = (const float*)d_in[5];
  const float* m1  = (const float*)d_in[6];
  const float* v1  = (const float*)d_in[7];
  const float* w2  = (const float*)d_in[8];
  const float* b2  = (const float*)d_in[9];
  const float* g2  = (const float*)d_in[10];
  const float* be2 = (const float*)d_in[11];
  const float* m2  = (const float*)d_in[12];
  const float* v2  = (const float*)d_in[13];
  const float* w3  = (const float*)d_in[14];
  const float* b3  = (const float*)d_in[15];
  const float* w4  = (const float*)d_in[16];
  const float* b4  = (const float*)d_in[17];
  const float* w5  = (const float*)d_in[18];
  const float* b5  = (const float*)d_in[19];
  float* out = (float*)d_out;

  char* ws = (char*)d_ws;
  ushort* w1b  = (ushort*)ws;             // 73728 B
  ushort* w2b  = (ushort*)(ws + 73728);   // 73728 B
  float* fbase = (float*)(ws + 147456);
  float* u3    = fbase;                   // 192
  float* u4    = fbase + 192;             // 392
  float* cvecs = fbase + 584;             // 384 (c1|c2)
  float* Kc    = fbase + 968;             // 1

  prep_kernel<<<211, 256, 0, stream>>>(w1, b1, g1, be1, m1, v1,
                                       w2, b2, g2, be2, m2, v2,
                                       w3, b3, w4, b4, w5, b5,
                                       w1b, w2b, u3, u4, cvecs, Kc);
  fused_kernel<<<256, 768, SMEM_BYTES, stream>>>(x, y, w1b, w2b, cvecs, u4,
                                                 u3, Kc, out);
}

// Round 17
// 60.983 us; speedup vs baseline: 1.1094x; 1.0064x over previous
//
#include <hip/hip_runtime.h>
#include <hip/hip_bf16.h>

typedef __attribute__((ext_vector_type(8))) short bf16x8;
typedef __attribute__((ext_vector_type(4))) float f32x4;

#define CDIM 192
#define NTOK 196
#define LTOT 392
#define NBE 64

__device__ __forceinline__ ushort f2bf(float f) {
  uint u = __float_as_uint(f);
  u = (u + 0x7FFFu + ((u >> 16) & 1u)) >> 16;
  return (ushort)u;
}
__device__ __forceinline__ float bf2f(ushort h) {
  return __uint_as_float(((uint)h) << 16);
}
__device__ __forceinline__ uint pk2(float lo, float hi) {
  __hip_bfloat162 t = __float22bfloat162_rn(float2{lo, hi});
  uint r;
  __builtin_memcpy(&r, &t, 4);
  return r;
}
__device__ __forceinline__ float wave_reduce(float a) {
#pragma unroll
  for (int off = 32; off > 0; off >>= 1) a += __shfl_xor(a, off);
  return a;
}
// Raw barrier: LDS-visibility only (lgkmcnt); does NOT drain in-flight global
// loads (unlike __syncthreads' vmcnt(0) drain) — keeps prefetches pipelined.
__device__ __forceinline__ void barL() {
  asm volatile("s_waitcnt lgkmcnt(0)" ::: "memory");
  __builtin_amdgcn_s_barrier();
  __builtin_amdgcn_sched_barrier(0);
}

// ---------------- prep: fold BN (bf16 weights), u3/u4/K via wave-reductions ---
__global__ __launch_bounds__(256) void prep_kernel(
    const float* __restrict__ w1, const float* __restrict__ b1, const float* __restrict__ g1,
    const float* __restrict__ be1, const float* __restrict__ m1, const float* __restrict__ v1,
    const float* __restrict__ w2, const float* __restrict__ b2, const float* __restrict__ g2,
    const float* __restrict__ be2, const float* __restrict__ m2, const float* __restrict__ v2,
    const float* __restrict__ w3, const float* __restrict__ b3,
    const float* __restrict__ w4, const float* __restrict__ b4,
    const float* __restrict__ w5, const float* __restrict__ b5,
    ushort* __restrict__ w1b, ushort* __restrict__ w2b,
    float* __restrict__ u3, float* __restrict__ u4, float* __restrict__ cvecs,
    float* __restrict__ Kc) {
  const int bid = blockIdx.x;
  const int wid = threadIdx.x >> 6, lane = threadIdx.x & 63;
  if (bid < NBE) {
    for (int i = bid * 256 + threadIdx.x; i < 74112; i += NBE * 256) {
      if (i < 36864) {
        int o = i / CDIM;
        float inv = g1[o] * rsqrtf(v1[o] + 1e-5f);
        w1b[i] = f2bf(w1[i] * inv);
      } else if (i < 73728) {
        int j = i - 36864; int o = j / CDIM;
        float inv = g2[o] * rsqrtf(v2[o] + 1e-5f);
        w2b[j] = f2bf(w2[j] * inv);
      } else {
        int k = i - 73728; int h = k / CDIM, o = k % CDIM;
        const float* bb = h ? b2 : b1; const float* gg = h ? g2 : g1;
        const float* bee = h ? be2 : be1;
        const float* mm = h ? m2 : m1; const float* vv = h ? v2 : v1;
        float inv = gg[o] * rsqrtf(vv[o] + 1e-5f);
        cvecs[k] = (bb[o] - mm[o]) * inv + bee[o];
      }
    }
  } else if (bid < NBE + 48) {            // u3: wave per output j
    int j = (bid - NBE) * 4 + wid;
    float a = 0.f;
    for (int c = lane; c < CDIM; c += 64) a += w5[c] * w3[c * CDIM + j];
    a = wave_reduce(a);
    if (lane == 0) u3[j] = a;
  } else if (bid < NBE + 48 + 98) {       // u4: wave per output j
    int j = (bid - NBE - 48) * 4 + wid;
    float a = 0.f;
    for (int o = lane; o < 784; o += 64)
      a += w5[CDIM + o] * (w4[o * 784 + j] + w4[o * 784 + j + LTOT]);
    a = wave_reduce(a);
    if (lane == 0) u4[j] = a;
  } else {                                // Kc: single wave
    if (wid == 0) {
      float a = 0.f;
      for (int i = lane; i < CDIM + 784; i += 64)
        a += (i < CDIM) ? w5[i] * b3[i] : w5[i] * b4[i - CDIM];
      a = wave_reduce(a);
      if (lane == 0) Kc[0] = a + b5[0];
    }
  }
}

// --- fully fused: phi (in LDS) + s + W + out.  1 block per b, 12 waves. ------
// LDS: phiL[404*192]bf16 swz ^(l&7)<<4 | u4s[408] | csL[384] | sArr[192] | Wl[392]
#define PHIL_BYTES (404 * 384)
#define OFF_U4S PHIL_BYTES
#define OFF_CSL (OFF_U4S + 1632)
#define OFF_SARR (OFF_CSL + 1536)
#define OFF_WL (OFF_SARR + 768)
#define SMEM_BYTES (OFF_WL + 1568)

extern __shared__ char smem[];

__global__ __launch_bounds__(768, 1) void fused_kernel(
    const float* __restrict__ x, const float* __restrict__ y,
    const ushort* __restrict__ w1b, const ushort* __restrict__ w2b,
    const float* __restrict__ cvecs, const float* __restrict__ u4,
    const float* __restrict__ u3, const float* __restrict__ Kc,
    float* __restrict__ out) {
  const int b = blockIdx.x;
  ushort* phiL = (ushort*)smem;
  float* u4s = (float*)(smem + OFF_U4S);
  float* csL = (float*)(smem + OFF_CSL);
  float* sArr = (float*)(smem + OFF_SARR);
  float* Wl = (float*)(smem + OFF_WL);
  const int tid = threadIdx.x;
  for (int i = tid; i < 408; i += 768) u4s[i] = (i < LTOT) ? u4[i] : 0.f;
  for (int i = tid; i < 384; i += 768) csL[i] = cvecs[i];

  const int w = tid >> 6, lane = tid & 63;
  const int lrow = lane & 15, kgrp = lane >> 4;
  const int c = w * 16 + lrow;            // wave w owns c-tile w (12 waves)

  bf16x8 bfr[6];                          // current half's B-frags
#pragma unroll
  for (int kk = 0; kk < 6; kk++)
    bfr[kk] = *(const bf16x8*)(w1b + (size_t)c * CDIM + kk * 32 + kgrp * 8);

  const float4* xb4 = (const float4*)(x + (size_t)b * NTOK * CDIM);
  const float4* yb4 = (const float4*)(y + (size_t)b * NTOK * CDIM);
  float4 pfA[7], pfB[6];
  float sp = 0.f;

// chunk geometry: part0 = rows 0..111 (7 tiles, 5376 f4, no mask),
//                 part1 = rows 112..195 (6 tiles, 4032 f4, masked)
#define LOADC(PF, CNT, NF4, SRC4, ROW0) do {                                   \
  _Pragma("unroll")                                                            \
  for (int p = 0; p < (CNT); p++) {                                            \
    const int fi = p * 768 + tid;                                              \
    (PF)[p] = (fi < (NF4)) ? (SRC4)[(ROW0) * 48 + fi]                          \
                           : float4{0.f, 0.f, 0.f, 0.f};                       \
  } } while (0)

#define STAGE(PF, CNT, NF4, H, ROW0) do {                                      \
  _Pragma("unroll")                                                            \
  for (int p = 0; p < (CNT); p++) {                                            \
    const int fi = p * 768 + tid;                                              \
    if (fi < (NF4)) {                                                          \
      const int l = (H) * NTOK + (ROW0) + fi / 48;                             \
      const int c4 = fi % 48;                                                  \
      uint2 wv;                                                                \
      wv.x = pk2((PF)[p].x, (PF)[p].y);                                        \
      wv.y = pk2((PF)[p].z, (PF)[p].w);                                        \
      uint addr = (uint)(l * 384 + c4 * 8) ^ (uint)((l & 7) << 4);             \
      *(uint2*)((char*)phiL + addr) = wv;                                      \
    } } } while (0)

#define MFMA_EPI(H, ROW0, NT, CSR) do {                                        \
  f32x4 acc[7];                                                                \
  _Pragma("unroll")                                                            \
  for (int tt = 0; tt < 7; tt++) acc[tt] = f32x4{0.f, 0.f, 0.f, 0.f};          \
  _Pragma("unroll")                                                            \
  for (int tt = 0; tt < 7; tt++) if (tt < (NT)) {                              \
    const int l0 = (H) * NTOK + (ROW0) + tt * 16 + lrow;                       \
    bf16x8 af[6];                                                              \
    _Pragma("unroll")                                                          \
    for (int kk = 0; kk < 6; kk++) {                                           \
      uint ad = (uint)(l0 * 384 + kk * 64 + kgrp * 16) ^ (uint)((l0 & 7) << 4);\
      af[kk] = *(const bf16x8*)((const char*)phiL + ad);                       \
    }                                                                          \
    _Pragma("unroll")                                                          \
    for (int kk = 0; kk < 6; kk++)                                             \
      acc[tt] = __builtin_amdgcn_mfma_f32_16x16x32_bf16(af[kk], bfr[kk],       \
                                                        acc[tt], 0, 0, 0);    \
  }                                                                            \
  barL(); /* all waves' A reads drained before phi overwrites */               \
  _Pragma("unroll")                                                            \
  for (int tt = 0; tt < 7; tt++) if (tt < (NT)) {                              \
    const float v0 = fmaxf(acc[tt][0] + (CSR), 0.f);                           \
    const float v1 = fmaxf(acc[tt][1] + (CSR), 0.f);                           \
    const float v2 = fmaxf(acc[tt][2] + (CSR), 0.f);                           \
    const float v3 = fmaxf(acc[tt][3] + (CSR), 0.f);                           \
    const uint p01 = pk2(v0, v1), p23 = pk2(v2, v3);                           \
    const int rw0 = (ROW0) + tt * 16 + 4 * kgrp;                               \
    _Pragma("unroll")                                                          \
    for (int j = 0; j < 4; j++) {                                              \
      const int row = rw0 + j;                                                 \
      if (row < NTOK) {                                                        \
        const int l = (H) * NTOK + row;                                        \
        uint addr = (uint)(l * 384 + c * 2) ^ (uint)((l & 7) << 4);            \
        const uint piece = (j == 0) ? (p01 & 0xFFFFu) : (j == 1) ? (p01 >> 16) \
                         : (j == 2) ? (p23 & 0xFFFFu) : (p23 >> 16);           \
        *(ushort*)((char*)phiL + addr) = (ushort)piece;                        \
        const float vj = (j == 0) ? v0 : (j == 1) ? v1 : (j == 2) ? v2 : v3;   \
        sp += u4s[l] * vj;                                                     \
      } } } } while (0)

  LOADC(pfA, 7, 5376, xb4, 0);            // chunk0 (x rows 0..111)
  LOADC(pfB, 6, 4032, xb4, 112);          // chunk1 (x rows 112..195)
  // chunk0
  STAGE(pfA, 7, 5376, 0, 0);              // progressive vmcnt drain
  LOADC(pfA, 7, 5376, yb4, 0);            // chunk2 in flight (2-chunk lead)
  barL();
  const float csr0 = csL[c], csr1 = csL[CDIM + c];
  MFMA_EPI(0, 0, 7, csr0);
  // chunk1
  STAGE(pfB, 6, 4032, 0, 112);
  LOADC(pfB, 6, 4032, yb4, 112);          // chunk3 in flight
  barL();
  MFMA_EPI(0, 112, 6, csr0);
  // switch B-frags to half 1 (L2-hot reload; covered by chunk2 stage wait)
#pragma unroll
  for (int kk = 0; kk < 6; kk++)
    bfr[kk] = *(const bf16x8*)(w2b + (size_t)c * CDIM + kk * 32 + kgrp * 8);
  // chunk2
  STAGE(pfA, 7, 5376, 1, 0);
  barL();
  MFMA_EPI(1, 0, 7, csr1);
  // chunk3
  STAGE(pfB, 6, 4032, 1, 112);
  barL();
  MFMA_EPI(1, 112, 6, csr1);

  // s reduction (c fixed per lane) -> sArr -> coeff
  sp += __shfl_xor(sp, 16);
  sp += __shfl_xor(sp, 32);
  if (kgrp == 0) sArr[c] = sp;
  barL();
  for (int i = tid; i < CDIM; i += 768) sArr[i] = u3[i] + sArr[i];
  barL();

  // W phase: MFMA lane layout (16 rows x 4 kgrp per wave) -> bank-balanced
  const float Kv = Kc[0];
#pragma unroll
  for (int p = 0; p < 3; p++) {
    const int row = p * 192 + w * 16 + lrow;
    float acc = 0.f;
    if (row < LTOT) {
#pragma unroll
      for (int kk = 0; kk < 6; kk++) {
        const int c0 = kk * 32 + kgrp * 8;
        uint addr = (uint)(row * 384 + c0 * 2) ^ (uint)((row & 7) << 4);
        const uint4 pv = *(const uint4*)((const char*)phiL + addr);
        const float4 cfa = *(const float4*)&sArr[c0];
        const float4 cfb = *(const float4*)&sArr[c0 + 4];
        acc += cfa.x * bf2f((ushort)pv.x) + cfa.y * bf2f((ushort)(pv.x >> 16))
             + cfa.z * bf2f((ushort)pv.y) + cfa.w * bf2f((ushort)(pv.y >> 16))
             + cfb.x * bf2f((ushort)pv.z) + cfb.y * bf2f((ushort)(pv.z >> 16))
             + cfb.z * bf2f((ushort)pv.w) + cfb.w * bf2f((ushort)(pv.w >> 16));
      }
    }
    acc += __shfl_xor(acc, 16);
    acc += __shfl_xor(acc, 32);
    if (kgrp == 0 && row < LTOT) Wl[row] = acc + Kv;
  }

  // out phase: 7 n-tiles of 28; tileF (stride 196, b128 writes) over dead phiL
  float* tileF = (float*)smem;
  const float* xb = x + (size_t)b * NTOK * CDIM;
  const float* yb = y + (size_t)b * NTOK * CDIM;
  float4 pxA[2], pyA[2], pxB[2], pyB[2];

#define LOADT(NT, PX, PY) do {                                                 \
  if ((NT) < 7) {                                                              \
    _Pragma("unroll")                                                          \
    for (int p = 0; p < 2; p++) {                                              \
      const int i = p * 768 + tid;                                             \
      if (i < 1344) {                                                          \
        const size_t xi = (size_t)((NT) * 28 + i / 48) * CDIM + (i % 48) * 4;  \
        (PX)[p] = *(const float4*)&xb[xi];                                     \
        (PY)[p] = *(const float4*)&yb[xi];                                     \
      } } } } while (0)

#define COMBINE(N0, PX, PY) do {                                               \
  _Pragma("unroll")                                                            \
  for (int p = 0; p < 2; p++) {                                                \
    const int i = p * 768 + tid;                                               \
    if (i < 1344) {                                                            \
      const int nl = i / 48, c4 = (i % 48) * 4;                                \
      const float wx = Wl[(N0) + nl], wy = Wl[NTOK + (N0) + nl];               \
      float4 o;                                                                \
      o.x = (PX)[p].x * wx + (PY)[p].x * wy;                                   \
      o.y = (PX)[p].y * wx + (PY)[p].y * wy;                                   \
      o.z = (PX)[p].z * wx + (PY)[p].z * wy;                                   \
      o.w = (PX)[p].w * wx + (PY)[p].w * wy;                                   \
      *(float4*)&tileF[nl * 196 + c4] = o;                                     \
    } } } while (0)

  LOADT(0, pxA, pyA);
  LOADT(1, pxB, pyB);
  for (int nt = 0; nt < 7; nt++) {
    const int n0 = nt * 28;
    barL();  // nt=0: W reads of phiL + Wl writes done; else: prev store done
    if (nt & 1) { COMBINE(n0, pxB, pyB); LOADT(nt + 2, pxB, pyB); }
    else        { COMBINE(n0, pxA, pyA); LOADT(nt + 2, pxA, pyA); }
    barL();  // tile written
#pragma unroll
    for (int p = 0; p < 2; p++) {
      const int i = p * 768 + tid;
      if (i < 1344) {
        const int cc = i / 7, nq = i % 7;
        float4 o;
        o.x = tileF[(nq * 4 + 0) * 196 + cc];
        o.y = tileF[(nq * 4 + 1) * 196 + cc];
        o.z = tileF[(nq * 4 + 2) * 196 + cc];
        o.w = tileF[(nq * 4 + 3) * 196 + cc];
        *(float4*)&out[((size_t)b * CDIM + cc) * NTOK + n0 + nq * 4] = o;
      }
    }
  }
}

extern "C" void kernel_launch(void* const* d_in, const int* in_sizes, int n_in,
                              void* d_out, int out_size, void* d_ws, size_t ws_size,
                              hipStream_t stream) {
  const float* x   = (const float*)d_in[0];
  const float* y   = (const float*)d_in[1];
  const float* w1  = (const float*)d_in[2];
  const float* b1  = (const float*)d_in[3];
  const float* g1  = (const float*)d_in[4];
  const float* be1 = (const float*)d_in[5];
  const float* m1  = (const float*)d_in[6];
  const float* v1  = (const float*)d_in[7];
  const float* w2  = (const float*)d_in[8];
  const float* b2  = (const float*)d_in[9];
  const float* g2  = (const float*)d_in[10];
  const float* be2 = (const float*)d_in[11];
  const float* m2  = (const float*)d_in[12];
  const float* v2  = (const float*)d_in[13];
  const float* w3  = (const float*)d_in[14];
  const float* b3  = (const float*)d_in[15];
  const float* w4  = (const float*)d_in[16];
  const float* b4  = (const float*)d_in[17];
  const float* w5  = (const float*)d_in[18];
  const float* b5  = (const float*)d_in[19];
  float* out = (float*)d_out;

  char* ws = (char*)d_ws;
  ushort* w1b  = (ushort*)ws;             // 73728 B
  ushort* w2b  = (ushort*)(ws + 73728);   // 73728 B
  float* fbase = (float*)(ws + 147456);
  float* u3    = fbase;                   // 192
  float* u4    = fbase + 192;             // 392
  float* cvecs = fbase + 584;             // 384 (c1|c2)
  float* Kc    = fbase + 968;             // 1

  prep_kernel<<<211, 256, 0, stream>>>(w1, b1, g1, be1, m1, v1,
                                       w2, b2, g2, be2, m2, v2,
                                       w3, b3, w4, b4, w5, b5,
                                       w1b, w2b, u3, u4, cvecs, Kc);
  fused_kernel<<<256, 768, SMEM_BYTES, stream>>>(x, y, w1b, w2b, cvecs, u4,
                                                 u3, Kc, out);
}